// Round 8
// baseline (190.093 us; speedup 1.0000x reference)
//
#include <hip/hip_runtime.h>
#include <stdint.h>

typedef __bf16 bf16x8 __attribute__((ext_vector_type(8)));
typedef float f32x4 __attribute__((ext_vector_type(4)));

#define B_ 16
#define C_ 512
#define S_ 1024   // W*H = 32*32
#define N1 1536   // 3C

// ---------- bf16 helpers (manual RNE) ----------
__device__ inline unsigned short f2b(float f) {
    unsigned int u = __builtin_bit_cast(unsigned int, f);
    unsigned int lsb = (u >> 16) & 1u;
    u += 0x7fffu + lsb;
    return (unsigned short)(u >> 16);
}
__device__ inline float b2f(unsigned int s) {
    unsigned int u = (s & 0xffffu) << 16;
    return __builtin_bit_cast(float, u);
}

// async global->LDS, 16B per lane. LDS dest must be wave-uniform base + lane*16.
__device__ inline void gl_lds16(const unsigned short* g, unsigned short* l) {
    __builtin_amdgcn_global_load_lds(
        (const __attribute__((address_space(1))) void*)(g),
        (__attribute__((address_space(3))) void*)(l),
        16, 0, 0);
}

// ---------- prep: w1,w2 -> bf16; zero sum planes (tiny; ~3 us) ----------
__global__ __launch_bounds__(256) void prep_misc(
    const float* __restrict__ w1, const float* __restrict__ w2,
    unsigned short* __restrict__ w1b, unsigned short* __restrict__ w2b,
    float* __restrict__ sums)
{
    int base = blockIdx.x * 256 + threadIdx.x; // 128 blocks -> 32768 threads
    for (int i = base; i < 292864; i += 32768) {
        if (i < 196608) {
            float4 v = ((const float4*)w1)[i];
            ((ushort4*)w1b)[i] = make_ushort4(f2b(v.x), f2b(v.y), f2b(v.z), f2b(v.w));
        } else if (i < 262144) {
            int j = i - 196608;
            float4 v = ((const float4*)w2)[j];
            ((ushort4*)w2b)[j] = make_ushort4(f2b(v.x), f2b(v.y), f2b(v.z), f2b(v.w));
        } else {
            int j = i - 262144;
            ((float4*)sums)[j] = make_float4(0.f, 0.f, 0.f, 0.f);
        }
    }
}

// ---------- gemm1_fx: 128x128 tile, BK=64, 4 waves; A staged DIRECTLY from x (f32) ----------
// Fuses the transpose+convert into A-staging (T14 reg-staging, gemm2_fused-proven pattern):
//   issueA (phase 0): lane l owns row r=r0+l; 32 global_load_dword from x[b][c][s] --
//     per instruction 64 lanes = 256 B contiguous in s (perfect coalescing).
//   writeA (phase 1, after counted vmcnt): f2b-pack -> 4 ds_write_b128 into the proven
//     XOR-swizzled layout (LDS slot kc^(r&7) holds source chunk kc).
// vmcnt stream (per wave): steady [B(T+1):4][A(T+1):32][B(T+2):4] -> vmcnt(4); 0 @ T==6.
// B-path (gl_lds16 from w1b), frag reads, MFMA, epilogue, sums: byte-identical to R7.
__global__ __launch_bounds__(256, 2) void gemm1_fx(
    const float* __restrict__ x,
    const unsigned short* __restrict__ Wt,
    const float* __restrict__ bias,
    unsigned short* __restrict__ Y,
    float* __restrict__ Tsum, float* __restrict__ H0, float* __restrict__ H31,
    float* __restrict__ C0, float* __restrict__ C31)
{
    __shared__ __align__(16) unsigned short lds[32768]; // 64 KB: A@0/8192, B@16384/24576
    const int tid = threadIdx.x;
    const int lane = tid & 63, wid = tid >> 6;   // 4 waves
    const int wm = (wid >> 1) * 64;              // 0 / 64
    const int wn = (wid & 1) * 64;               // 0 / 64
    const int quad = lane >> 4, l16 = lane & 15;
    const int m0 = blockIdx.x * 128;
    const int n0 = blockIdx.y * 128;
    const int b = m0 >> 10, s0 = m0 & 1023;
    const unsigned short* Bb = Wt + (size_t)n0 * 512;

    // A-staging ownership: wave covers rows r0..r0+63 (r = r0+lane), k-chunks kc0..kc0+3
    const int r0 = (wid >> 1) * 64;
    const int kc0 = (wid & 1) * 4;
    const int rA = r0 + lane;                    // this thread's A row (= s offset)
    const float* xrow = x + ((size_t)b * C_) * S_ + s0 + rA; // + c*1024 later

    f32x4 acc[4][4] = {};
    float av[4][8];                              // in-flight A values (static-indexed)

    auto stageB = [&](int T) {
        unsigned short* dst = &lds[16384 + (T & 1) * 8192];
#pragma unroll
        for (int i = 0; i < 4; i++) {
            int ch = i * 256 + tid;
            int r = ch >> 3, kc = ch & 7;
            gl_lds16(Bb + (size_t)r * 512 + T * 64 + ((kc ^ (r & 7)) * 8), dst + ch * 8);
        }
    };
    auto issueA = [&](int T) {
#pragma unroll
        for (int i = 0; i < 4; i++) {
            int cbase = T * 64 + (kc0 + i) * 8;
#pragma unroll
            for (int j = 0; j < 8; j++)
                av[i][j] = xrow[(size_t)(cbase + j) * S_];
        }
    };
    auto writeA = [&](int T) {
        unsigned short* dst = &lds[(T & 1) * 8192];
#pragma unroll
        for (int i = 0; i < 4; i++) {
            unsigned int p[4];
#pragma unroll
            for (int k = 0; k < 4; k++)
                p[k] = (unsigned int)f2b(av[i][2 * k]) | ((unsigned int)f2b(av[i][2 * k + 1]) << 16);
            int slot = (kc0 + i) ^ (rA & 7);
            *(uint4*)&dst[rA * 64 + slot * 8] = *(const uint4*)p;
        }
    };

    // prologue: B0(4), A0-loads(32), B1(4) -> vmcnt(4): B0+A0 done, B1 in flight
    stageB(0);
    issueA(0);
    stageB(1);
    asm volatile("s_waitcnt vmcnt(4)" ::: "memory");
    writeA(0);
    asm volatile("s_waitcnt lgkmcnt(0)" ::: "memory");
    __builtin_amdgcn_s_barrier();

    for (int T = 0; T < 8; T++) {
        const unsigned short* Asl = &lds[(T & 1) * 8192];
        const unsigned short* Bsl = &lds[16384 + (T & 1) * 8192];
        bf16x8 bfr[4][2], af[2][2];
        // ---- phase 0: B frags (reused both phases) + A frags mt 0,1; issue A(T+1) loads ----
#pragma unroll
        for (int nt = 0; nt < 4; nt++)
#pragma unroll
            for (int kh = 0; kh < 2; kh++) {
                int rb = wn + nt * 16 + l16;
                bfr[nt][kh] = *(const bf16x8*)&Bsl[rb * 64 + (((kh * 4 + quad) ^ (rb & 7)) * 8)];
            }
#pragma unroll
        for (int mi = 0; mi < 2; mi++)
#pragma unroll
            for (int kh = 0; kh < 2; kh++) {
                int ra = wm + mi * 16 + l16;
                af[mi][kh] = *(const bf16x8*)&Asl[ra * 64 + (((kh * 4 + quad) ^ (ra & 7)) * 8)];
            }
        if (T < 7) issueA(T + 1);
        __builtin_amdgcn_s_barrier();
        asm volatile("s_waitcnt lgkmcnt(0)" ::: "memory");
        __builtin_amdgcn_sched_barrier(0);
        __builtin_amdgcn_s_setprio(1);
#pragma unroll
        for (int mi = 0; mi < 2; mi++)
#pragma unroll
            for (int nt = 0; nt < 4; nt++)
#pragma unroll
                for (int kh = 0; kh < 2; kh++)
                    acc[mi][nt] = __builtin_amdgcn_mfma_f32_16x16x32_bf16(
                        af[mi][kh], bfr[nt][kh], acc[mi][nt], 0, 0, 0);
        __builtin_amdgcn_s_setprio(0);
        __builtin_amdgcn_s_barrier();
        // ---- phase 1: A frags mt 2,3; stage B(T+2); counted wait; write A(T+1) ----
#pragma unroll
        for (int mi = 0; mi < 2; mi++)
#pragma unroll
            for (int kh = 0; kh < 2; kh++) {
                int ra = wm + (2 + mi) * 16 + l16;
                af[mi][kh] = *(const bf16x8*)&Asl[ra * 64 + (((kh * 4 + quad) ^ (ra & 7)) * 8)];
            }
        if (T < 6) {
            stageB(T + 2);
            asm volatile("s_waitcnt vmcnt(4)" ::: "memory"); // A(T+1)+B(T+1) done; B(T+2) in flight
            writeA(T + 1);
        } else if (T == 6) {
            asm volatile("s_waitcnt vmcnt(0)" ::: "memory"); // drain A7,B7
            writeA(T + 1);
        }
        __builtin_amdgcn_s_barrier();
        asm volatile("s_waitcnt lgkmcnt(0)" ::: "memory");
        __builtin_amdgcn_sched_barrier(0);
        __builtin_amdgcn_s_setprio(1);
#pragma unroll
        for (int mi = 0; mi < 2; mi++)
#pragma unroll
            for (int nt = 0; nt < 4; nt++)
#pragma unroll
                for (int kh = 0; kh < 2; kh++)
                    acc[2 + mi][nt] = __builtin_amdgcn_mfma_f32_16x16x32_bf16(
                        af[mi][kh], bfr[nt][kh], acc[2 + mi][nt], 0, 0, 0);
        __builtin_amdgcn_s_setprio(0);
        __builtin_amdgcn_s_barrier();
    }
    __syncthreads();

    // ---- epilogue: Y bf16 via swizzled 32KB LDS, 16B coalesced stores (R5-proven) ----
    {
        unsigned short* eb = lds; // 128*128 shorts
#pragma unroll
        for (int mt = 0; mt < 4; mt++)
#pragma unroll
            for (int nt = 0; nt < 4; nt++) {
                int col = wn + nt * 16 + l16;
                float bv = bias[n0 + col];
                int cc = col >> 3, cw = col & 7;
#pragma unroll
                for (int r = 0; r < 4; r++) {
                    int row = wm + mt * 16 + quad * 4 + r;
                    eb[row * 128 + (((cc ^ (row & 7)) << 3) + cw)] = f2b(acc[mt][nt][r] + bv);
                }
            }
        __syncthreads();
#pragma unroll
        for (int it = 0; it < 8; it++) {
            int cid = it * 256 + tid;        // 2048 16B-chunks
            int row = cid >> 4, j = cid & 15;
            bf16x8 v = *(const bf16x8*)&eb[row * 128 + ((j ^ (row & 7)) << 3)];
            *(bf16x8*)&Y[(size_t)(m0 + row) * N1 + n0 + j * 8] = v;
        }
    }

    // ---- fused a-sum accumulators (R1/R3-proven mapping; wm in {0,64}) ----
    {
        int wlo = (m0 & 1023) >> 5;
#pragma unroll
        for (int nt = 0; nt < 4; nt++) {
            int n = n0 + wn + nt * 16 + l16;
            float bv = bias[n];
            float tT = 0.f;
#pragma unroll
            for (int mt = 0; mt < 4; mt++)
#pragma unroll
                for (int r = 0; r < 4; r++) tT += acc[mt][nt][r] + bv;
            tT += __shfl_xor(tT, 16);
            tT += __shfl_xor(tT, 32);
            if (quad == 0) {
                atomicAdd(&Tsum[b * 1536 + n], tT);
                float th0 = acc[0][nt][0] + acc[2][nt][0] + 2.f * bv;
                atomicAdd(&H0[b * 1536 + n], th0);
            }
            if (quad == 3) {
                float th31 = acc[1][nt][3] + acc[3][nt][3] + 2.f * bv;
                atomicAdd(&H31[b * 1536 + n], th31);
            }
            if (wlo == 0 && wm == 0) {
                float tc = 0.f;
#pragma unroll
                for (int mt = 0; mt < 2; mt++)
#pragma unroll
                    for (int r = 0; r < 4; r++) tc += acc[mt][nt][r] + bv;
                tc += __shfl_xor(tc, 16);
                tc += __shfl_xor(tc, 32);
                if (quad == 0) atomicAdd(&C0[b * 1536 + n], tc);
            }
            if (wlo == 28 && wm == 64) {
                float tc = 0.f;
#pragma unroll
                for (int mt = 2; mt < 4; mt++)
#pragma unroll
                    for (int r = 0; r < 4; r++) tc += acc[mt][nt][r] + bv;
                tc += __shfl_xor(tc, 16);
                tc += __shfl_xor(tc, 32);
                if (quad == 0) atomicAdd(&C31[b * 1536 + n], tc);
            }
        }
    }
}

// ---------- gemm2 with FUSED combine+softmax in A-staging (R4-proven) ----------
__global__ __launch_bounds__(512, 2) void gemm2_fused(
    const unsigned short* __restrict__ Yg,
    const float* __restrict__ hat,
    const unsigned short* __restrict__ Wt,
    const float* __restrict__ bias,
    float* __restrict__ O)
{
    __shared__ __align__(16) unsigned short As[2 * 8192];   // 2 x 16 KB
    __shared__ __align__(16) unsigned short Bs[2 * 16384];  // 2 x 32 KB
    __shared__ float gs[3][512];                            // 6 KB
    const int tid = threadIdx.x;
    const int lane = tid & 63, wid = tid >> 6;
    const int wm = (wid >> 2) * 64;
    const int wn = (wid & 3) * 64;
    const int quad = lane >> 4, l16 = lane & 15;
    const int m0 = blockIdx.x * 128;
    const int n0 = blockIdx.y * 256;
    const int b = m0 >> 10, s0 = m0 & 1023, w0 = s0 >> 5;
    const int bq = b * 1024;
    const unsigned short* Bb = Wt + (size_t)n0 * 512;
    const int chunk = tid & 7, mpair = tid >> 3;

    f32x4 acc[4][4] = {};

    {
        int c = tid;
        float h0v = hat[b * 1536 + c];
        float h1v = hat[b * 1536 + 512 + c];
        float h2v = hat[b * 1536 + 1024 + c];
        float mx = fmaxf(h0v, fmaxf(h1v, h2v));
        float e0 = __expf(h0v - mx), e1 = __expf(h1v - mx), e2 = __expf(h2v - mx);
        float inv = 1.0f / (e0 + e1 + e2);
        gs[0][c] = e0 * inv; gs[1][c] = e1 * inv; gs[2][c] = e2 * inv;
    }
    __syncthreads();

    auto stageB = [&](int T) {
        unsigned short* dst = &Bs[(T & 1) * 16384];
#pragma unroll
        for (int i = 0; i < 4; i++) {
            int ch = i * 512 + tid;
            int r = ch >> 3, kc = ch & 7;
            gl_lds16(Bb + (size_t)r * 512 + T * 64 + ((kc ^ (r & 7)) * 8), dst + ch * 8);
        }
    };

    uint4 u1[2], u2[2], u3[2];
    auto issueA = [&](int Tn) {
        int q = Tn >> 1;
        int dw1 = (q == 0) ? -1 : (q == 1) ? 1 : 0;
        int dh1 = (q == 2) ? -1 : (q == 3) ? 1 : 0;
        int dh2 = (q == 0) ? -1 : (q == 1) ? 1 : 0;
        int dw2 = (q == 2) ? -1 : (q == 3) ? 1 : 0;
        int cg = Tn * 64 + chunk * 8;
#pragma unroll
        for (int j = 0; j < 2; j++) {
            int ml = mpair * 2 + j;
            int w = w0 + (ml >> 5), h = ml & 31;
            int r1 = bq + min(max(w + dw1, 0), 31) * 32 + min(max(h + dh1, 0), 31);
            int r2 = bq + min(max(w + dw2, 0), 31) * 32 + min(max(h + dh2, 0), 31);
            int r3 = bq + w * 32 + h;
            u1[j] = *(const uint4*)&Yg[(size_t)r1 * 1536 + cg];
            u2[j] = *(const uint4*)&Yg[(size_t)r2 * 1536 + 512 + cg];
            u3[j] = *(const uint4*)&Yg[(size_t)r3 * 1536 + 1024 + cg];
        }
    };
    auto writeA = [&](int Tn) {
        int cg = Tn * 64 + chunk * 8;
        float g0v[8], g1v[8], g2v[8];
        *(float4*)&g0v[0] = *(const float4*)&gs[0][cg];
        *(float4*)&g0v[4] = *(const float4*)&gs[0][cg + 4];
        *(float4*)&g1v[0] = *(const float4*)&gs[1][cg];
        *(float4*)&g1v[4] = *(const float4*)&gs[1][cg + 4];
        *(float4*)&g2v[0] = *(const float4*)&gs[2][cg];
        *(float4*)&g2v[4] = *(const float4*)&gs[2][cg + 4];
#pragma unroll
        for (int j = 0; j < 2; j++) {
            const unsigned int* a1 = (const unsigned int*)&u1[j];
            const unsigned int* a2 = (const unsigned int*)&u2[j];
            const unsigned int* a3 = (const unsigned int*)&u3[j];
            unsigned int p[4];
#pragma unroll
            for (int k = 0; k < 4; k++) {
                float lo = g0v[2 * k] * b2f(a1[k]) + g1v[2 * k] * b2f(a2[k]) + g2v[2 * k] * b2f(a3[k]);
                float hi = g0v[2 * k + 1] * b2f(a1[k] >> 16) + g1v[2 * k + 1] * b2f(a2[k] >> 16) + g2v[2 * k + 1] * b2f(a3[k] >> 16);
                p[k] = (unsigned int)f2b(lo) | ((unsigned int)f2b(hi) << 16);
            }
            int ml = mpair * 2 + j;
            *(uint4*)&As[(Tn & 1) * 8192 + ml * 64 + ((chunk ^ (ml & 7)) * 8)] = *(const uint4*)p;
        }
    };

    stageB(0);
    issueA(0);
    stageB(1);
    asm volatile("s_waitcnt vmcnt(4)" ::: "memory");
    writeA(0);
    asm volatile("s_waitcnt lgkmcnt(0)" ::: "memory");
    __builtin_amdgcn_s_barrier();

    for (int T = 0; T < 8; T++) {
        const unsigned short* Asl = &As[(T & 1) * 8192];
        const unsigned short* Bsl = &Bs[(T & 1) * 16384];
        bf16x8 bfr[4][2], af[2][2];
#pragma unroll
        for (int nt = 0; nt < 4; nt++)
#pragma unroll
            for (int kh = 0; kh < 2; kh++) {
                int rb = wn + nt * 16 + l16;
                bfr[nt][kh] = *(const bf16x8*)&Bsl[rb * 64 + (((kh * 4 + quad) ^ (rb & 7)) * 8)];
            }
#pragma unroll
        for (int mi = 0; mi < 2; mi++)
#pragma unroll
            for (int kh = 0; kh < 2; kh++) {
                int ra = wm + mi * 16 + l16;
                af[mi][kh] = *(const bf16x8*)&Asl[ra * 64 + (((kh * 4 + quad) ^ (ra & 7)) * 8)];
            }
        if (T < 7) issueA(T + 1);
        __builtin_amdgcn_s_barrier();
        asm volatile("s_waitcnt lgkmcnt(0)" ::: "memory");
        __builtin_amdgcn_sched_barrier(0);
        __builtin_amdgcn_s_setprio(1);
#pragma unroll
        for (int mi = 0; mi < 2; mi++)
#pragma unroll
            for (int nt = 0; nt < 4; nt++)
#pragma unroll
                for (int kh = 0; kh < 2; kh++)
                    acc[mi][nt] = __builtin_amdgcn_mfma_f32_16x16x32_bf16(
                        af[mi][kh], bfr[nt][kh], acc[mi][nt], 0, 0, 0);
        __builtin_amdgcn_s_setprio(0);
        __builtin_amdgcn_s_barrier();
#pragma unroll
        for (int mi = 0; mi < 2; mi++)
#pragma unroll
            for (int kh = 0; kh < 2; kh++) {
                int ra = wm + (2 + mi) * 16 + l16;
                af[mi][kh] = *(const bf16x8*)&Asl[ra * 64 + (((kh * 4 + quad) ^ (ra & 7)) * 8)];
            }
        if (T < 6) stageB(T + 2);
        if (T < 7) {
            if (T < 6) asm volatile("s_waitcnt vmcnt(4)" ::: "memory");
            else       asm volatile("s_waitcnt vmcnt(0)" ::: "memory");
            writeA(T + 1);
        }
        __builtin_amdgcn_s_barrier();
        asm volatile("s_waitcnt lgkmcnt(0)" ::: "memory");
        __builtin_amdgcn_sched_barrier(0);
        __builtin_amdgcn_s_setprio(1);
#pragma unroll
        for (int mi = 0; mi < 2; mi++)
#pragma unroll
            for (int nt = 0; nt < 4; nt++)
#pragma unroll
                for (int kh = 0; kh < 2; kh++)
                    acc[2 + mi][nt] = __builtin_amdgcn_mfma_f32_16x16x32_bf16(
                        af[mi][kh], bfr[nt][kh], acc[2 + mi][nt], 0, 0, 0);
        __builtin_amdgcn_s_setprio(0);
        __builtin_amdgcn_s_barrier();
    }

    float* ef = (float*)Bs;
#pragma unroll
    for (int p = 0; p < 2; p++) {
        if (((wid & 3) >> 1) == p) {
#pragma unroll
            for (int mt = 0; mt < 4; mt++)
#pragma unroll
                for (int nt = 0; nt < 4; nt++) {
                    int nl = wn - p * 128 + nt * 16 + l16;
                    float bv = bias[n0 + p * 128 + nl];
                    int c = (wm >> 2) + mt * 4 + quad;
                    f32x4 v;
#pragma unroll
                    for (int r = 0; r < 4; r++) v[r] = acc[mt][nt][r] + bv;
                    *(f32x4*)&ef[nl * 128 + ((c ^ (nl & 7)) << 2)] = v;
                }
        }
        __syncthreads();
#pragma unroll
        for (int it = 0; it < 8; it++) {
            int cid = it * 512 + tid;
            int nl = cid >> 5, j = cid & 31;
            f32x4 v = *(const f32x4*)&ef[nl * 128 + ((j ^ (nl & 7)) << 2)];
            *(f32x4*)&O[((size_t)(b * 512 + n0 + p * 128 + nl)) * 1024 + s0 + j * 4] = v;
        }
        if (p == 0) __syncthreads();
    }
}

// ---------- layer1 ----------
__global__ __launch_bounds__(256) void mlp_layer1(
    const float* __restrict__ sums, const float* __restrict__ wa,
    const float* __restrict__ ba, float* __restrict__ h)
{
    __shared__ float sa[512];
    int b = blockIdx.x >> 7;
    int t = threadIdx.x;
    const float* Tp   = sums;
    const float* H0p  = sums + 24576;
    const float* H31p = sums + 49152;
    const float* C0p  = sums + 73728;
    const float* C31p = sums + 98304;
#pragma unroll
    for (int j = 0; j < 2; j++) {
        int c = t + j * 256;
        int q = c >> 7;
        int n1 = b * 1536 + c;
        float t123 = Tp[n1] + Tp[n1 + 512] + Tp[n1 + 1024];
        float sC1 = C0p[n1] - C31p[n1];
        float sH1 = H0p[n1] - H31p[n1];
        float sC2 = C0p[n1 + 512] - C31p[n1 + 512];
        float sH2 = H0p[n1 + 512] - H31p[n1 + 512];
        float e = (q < 2) ? (sC1 + sH2) : (sH1 + sC2);
        sa[c] = t123 + ((q & 1) ? -e : e);
    }
    __syncthreads();
    int lane = t & 63, wid = t >> 6;
    int o = (blockIdx.x & 127) * 4 + wid;
    const float4* wr = (const float4*)(wa + (size_t)o * 512);
    float4 w0 = wr[lane * 2], w1v = wr[lane * 2 + 1];
    float4 a0 = ((const float4*)sa)[lane * 2], a1 = ((const float4*)sa)[lane * 2 + 1];
    float dot = w0.x * a0.x + w0.y * a0.y + w0.z * a0.z + w0.w * a0.w
              + w1v.x * a1.x + w1v.y * a1.y + w1v.z * a1.z + w1v.w * a1.w;
#pragma unroll
    for (int off = 32; off; off >>= 1) dot += __shfl_down(dot, off);
    if (lane == 0) {
        float v = dot + ba[o];
        h[b * 512 + o] = 0.5f * v * (1.0f + erff(v * 0.7071067811865475f));
    }
}

// ---------- layer2: h staged in LDS; 16 o's per block (4 per wave) ----------
__global__ __launch_bounds__(256) void mlp_layer2(
    const float* __restrict__ h, const float* __restrict__ wb,
    const float* __restrict__ bb, float* __restrict__ hat)
{
    __shared__ float sh[512];
    int b = blockIdx.x / 96;
    int og = blockIdx.x - b * 96;
    int t = threadIdx.x;
    sh[t] = h[b * 512 + t];
    sh[t + 256] = h[b * 512 + 256 + t];
    __syncthreads();
    int lane = t & 63, wid = t >> 6;
    float4 a0 = ((const float4*)sh)[lane * 2], a1 = ((const float4*)sh)[lane * 2 + 1];
#pragma unroll
    for (int i = 0; i < 4; i++) {
        int o = og * 16 + wid * 4 + i;
        const float4* wr = (const float4*)(wb + (size_t)o * 512);
        float4 w0 = wr[lane * 2], w1 = wr[lane * 2 + 1];
        float dot = w0.x * a0.x + w0.y * a0.y + w0.z * a0.z + w0.w * a0.w
                  + w1.x * a1.x + w1.y * a1.y + w1.z * a1.z + w1.w * a1.w;
#pragma unroll
        for (int off = 32; off; off >>= 1) dot += __shfl_down(dot, off);
        if (lane == 0)
            hat[(size_t)b * 1536 + o] = dot + bb[o];
    }
}

extern "C" void kernel_launch(void* const* d_in, const int* in_sizes, int n_in,
                              void* d_out, int out_size, void* d_ws, size_t ws_size,
                              hipStream_t stream) {
    const float* x  = (const float*)d_in[0];
    const float* w1 = (const float*)d_in[1];
    const float* b1 = (const float*)d_in[2];
    const float* wa = (const float*)d_in[3];
    const float* ba = (const float*)d_in[4];
    const float* wb = (const float*)d_in[5];
    const float* bb = (const float*)d_in[6];
    const float* w2 = (const float*)d_in[7];
    const float* b2 = (const float*)d_in[8];
    float* out = (float*)d_out;

    char* ws = (char*)d_ws;
    unsigned short* w1b  = (unsigned short*)(ws + 16777216);   // 1.5 MB
    unsigned short* w2b  = (unsigned short*)(ws + 18350080);   // 0.5 MB
    unsigned short* y    = (unsigned short*)(ws + 18874368);   // 48 MB: (B,S,3C) bf16
    float* sums          = (float*)(ws + 69206016);            // 5 x 96 KB
    float* h_buf         = (float*)(ws + 69697536);            // 32 KB
    float* hat_buf       = (float*)(ws + 69730304);            // 96 KB

    float* Tsum = sums;
    float* H0   = sums + 24576;
    float* H31  = sums + 49152;
    float* C0   = sums + 73728;
    float* C31  = sums + 98304;

    prep_misc<<<dim3(128), dim3(256), 0, stream>>>(w1, w2, w1b, w2b, sums);
    gemm1_fx<<<dim3(128, 12), dim3(256), 0, stream>>>(
        x, w1b, b1, y, Tsum, H0, H31, C0, C31);
    mlp_layer1<<<dim3(2048), dim3(256), 0, stream>>>(sums, wa, ba, h_buf);
    mlp_layer2<<<dim3(1536), dim3(256), 0, stream>>>(h_buf, wb, bb, hat_buf);
    gemm2_fused<<<dim3(128, 2), dim3(512), 0, stream>>>(
        y, hat_buf, w2b, b2, out);
}

// Round 9
// 183.533 us; speedup vs baseline: 1.0357x; 1.0357x over previous
//
#include <hip/hip_runtime.h>
#include <stdint.h>

typedef __bf16 bf16x8 __attribute__((ext_vector_type(8)));
typedef float f32x4 __attribute__((ext_vector_type(4)));

#define B_ 16
#define C_ 512
#define S_ 1024   // W*H = 32*32
#define N1 1536   // 3C

// ---------- bf16 helpers (manual RNE) ----------
__device__ inline unsigned short f2b(float f) {
    unsigned int u = __builtin_bit_cast(unsigned int, f);
    unsigned int lsb = (u >> 16) & 1u;
    u += 0x7fffu + lsb;
    return (unsigned short)(u >> 16);
}
__device__ inline float b2f(unsigned int s) {
    unsigned int u = (s & 0xffffu) << 16;
    return __builtin_bit_cast(float, u);
}

// async global->LDS, 16B per lane. LDS dest must be wave-uniform base + lane*16.
__device__ inline void gl_lds16(const unsigned short* g, unsigned short* l) {
    __builtin_amdgcn_global_load_lds(
        (const __attribute__((address_space(1))) void*)(g),
        (__attribute__((address_space(3))) void*)(l),
        16, 0, 0);
}

// T1 bijective XCD swizzle (nwg % 8 == 0): HW round-robins blockIdx across XCDs;
// orig = (bid&7)*cpx + (bid>>3) gives each XCD a CONTIGUOUS orig chunk.
__device__ inline int xcd_orig(int bid, int nwg) {
    int cpx = nwg >> 3;
    return (bid & 7) * cpx + (bid >> 3);
}

// ---------- prep: x (B,C,S) f32 -> xT (B,S,C) bf16 (vectorized), + fused misc ----------
__global__ __launch_bounds__(256) void transpose_convert_x(
    const float* __restrict__ x, unsigned short* __restrict__ xT,
    const float* __restrict__ w1, const float* __restrict__ w2,
    unsigned short* __restrict__ w1b, unsigned short* __restrict__ w2b,
    float* __restrict__ sums)
{
    int t = threadIdx.x;
    if (blockIdx.z == 16) {
        int base = (blockIdx.y * 16 + blockIdx.x) * 256 + t; // 32768 threads
        for (int i = base; i < 292864; i += 32768) {
            if (i < 196608) {
                float4 v = ((const float4*)w1)[i];
                ((ushort4*)w1b)[i] = make_ushort4(f2b(v.x), f2b(v.y), f2b(v.z), f2b(v.w));
            } else if (i < 262144) {
                int j = i - 196608;
                float4 v = ((const float4*)w2)[j];
                ((ushort4*)w2b)[j] = make_ushort4(f2b(v.x), f2b(v.y), f2b(v.z), f2b(v.w));
            } else {
                int j = i - 262144;
                ((float4*)sums)[j] = make_float4(0.f, 0.f, 0.f, 0.f);
            }
        }
        return;
    }
    __shared__ float tile[64][68];
    int b = blockIdx.z;
    int c0 = blockIdx.y * 64;
    int s0 = blockIdx.x * 64;
    int r = t >> 2, q4 = t & 3;
    const float* xp = x + ((size_t)(b * C_ + c0 + r)) * S_ + s0;
#pragma unroll
    for (int k = 0; k < 4; k++) {
        float4 v = ((const float4*)xp)[q4 + 4 * k];
        *(float4*)&tile[r][(q4 + 4 * k) * 4] = v;
    }
    __syncthreads();
    int sr = t >> 2; // output s-row
    unsigned short* op = xT + ((size_t)(b * S_ + s0 + sr)) * C_ + c0;
#pragma unroll
    for (int kk = 0; kk < 2; kk++) {
        int chunk = q4 + 4 * kk;
        unsigned int pz[4];
#pragma unroll
        for (int i2 = 0; i2 < 4; i2++) {
            int c = chunk * 8 + i2 * 2;
            pz[i2] = (unsigned int)f2b(tile[c][sr]) | ((unsigned int)f2b(tile[c + 1][sr]) << 16);
        }
        *(uint4*)&op[chunk * 8] = make_uint4(pz[0], pz[1], pz[2], pz[3]);
    }
}

// ---------- gemm1: 128x256 tile, BK=64, 8 waves, 2-phase counted-vmcnt (R3/R4-proven) ----------
// + T1 XCD swizzle: each XCD owns a contiguous 96-orig chunk = one by-group ->
//   shared B panel (256KB) XCD-L2-resident.
template <bool DO_SUMS>
__global__ __launch_bounds__(512, 2) void gemm_2ph(
    const unsigned short* __restrict__ A,
    const unsigned short* __restrict__ Wt,
    const float* __restrict__ bias,
    unsigned short* __restrict__ Y,
    float* __restrict__ Tsum, float* __restrict__ H0, float* __restrict__ H31,
    float* __restrict__ C0, float* __restrict__ C31)
{
    __shared__ __align__(16) unsigned short lds[49152]; // 96 KB
    const int tid = threadIdx.x;
    const int lane = tid & 63, wid = tid >> 6;
    const int wm = (wid >> 2) * 64;   // 0 / 64
    const int wn = (wid & 3) * 64;    // 0,64,128,192
    const int quad = lane >> 4, l16 = lane & 15;
    const int orig = xcd_orig(blockIdx.y * 128 + blockIdx.x, 768);
    const int m0 = (orig & 127) * 128;
    const int n0 = (orig >> 7) * 256;
    const unsigned short* Ab = A + (size_t)m0 * 512;
    const unsigned short* Bb = Wt + (size_t)n0 * 512;

    f32x4 acc[4][4] = {};

    auto stageA = [&](int T) {
        unsigned short* dst = &lds[(T & 1) * 8192];
#pragma unroll
        for (int i = 0; i < 2; i++) {
            int ch = i * 512 + tid;
            int r = ch >> 3, kc = ch & 7;
            gl_lds16(Ab + (size_t)r * 512 + T * 64 + ((kc ^ (r & 7)) * 8), dst + ch * 8);
        }
    };
    auto stageB = [&](int T) {
        unsigned short* dst = &lds[16384 + (T & 1) * 16384];
#pragma unroll
        for (int i = 0; i < 4; i++) {
            int ch = i * 512 + tid;
            int r = ch >> 3, kc = ch & 7;
            gl_lds16(Bb + (size_t)r * 512 + T * 64 + ((kc ^ (r & 7)) * 8), dst + ch * 8);
        }
    };

    stageB(0); stageA(0); stageB(1);
    asm volatile("s_waitcnt vmcnt(4)" ::: "memory");
    __builtin_amdgcn_s_barrier();

    for (int T = 0; T < 8; T++) {
        const unsigned short* Asl = &lds[(T & 1) * 8192];
        const unsigned short* Bsl = &lds[16384 + (T & 1) * 16384];
        bf16x8 bfr[4][2], af[2][2];
        // ---- phase 0 ----
#pragma unroll
        for (int nt = 0; nt < 4; nt++)
#pragma unroll
            for (int kh = 0; kh < 2; kh++) {
                int rb = wn + nt * 16 + l16;
                bfr[nt][kh] = *(const bf16x8*)&Bsl[rb * 64 + (((kh * 4 + quad) ^ (rb & 7)) * 8)];
            }
#pragma unroll
        for (int mi = 0; mi < 2; mi++)
#pragma unroll
            for (int kh = 0; kh < 2; kh++) {
                int ra = wm + mi * 16 + l16;
                af[mi][kh] = *(const bf16x8*)&Asl[ra * 64 + (((kh * 4 + quad) ^ (ra & 7)) * 8)];
            }
        if (T < 7) stageA(T + 1);
        __builtin_amdgcn_s_barrier();
        asm volatile("s_waitcnt lgkmcnt(0)" ::: "memory");
        __builtin_amdgcn_sched_barrier(0);
        __builtin_amdgcn_s_setprio(1);
#pragma unroll
        for (int mi = 0; mi < 2; mi++)
#pragma unroll
            for (int nt = 0; nt < 4; nt++)
#pragma unroll
                for (int kh = 0; kh < 2; kh++)
                    acc[mi][nt] = __builtin_amdgcn_mfma_f32_16x16x32_bf16(
                        af[mi][kh], bfr[nt][kh], acc[mi][nt], 0, 0, 0);
        __builtin_amdgcn_s_setprio(0);
        __builtin_amdgcn_s_barrier();
        // ---- phase 1 ----
#pragma unroll
        for (int mi = 0; mi < 2; mi++)
#pragma unroll
            for (int kh = 0; kh < 2; kh++) {
                int ra = wm + (2 + mi) * 16 + l16;
                af[mi][kh] = *(const bf16x8*)&Asl[ra * 64 + (((kh * 4 + quad) ^ (ra & 7)) * 8)];
            }
        if (T < 6) {
            stageB(T + 2);
            asm volatile("s_waitcnt vmcnt(4)" ::: "memory");
        } else if (T == 6) {
            asm volatile("s_waitcnt vmcnt(0)" ::: "memory");
        }
        __builtin_amdgcn_s_barrier();
        asm volatile("s_waitcnt lgkmcnt(0)" ::: "memory");
        __builtin_amdgcn_sched_barrier(0);
        __builtin_amdgcn_s_setprio(1);
#pragma unroll
        for (int mi = 0; mi < 2; mi++)
#pragma unroll
            for (int nt = 0; nt < 4; nt++)
#pragma unroll
                for (int kh = 0; kh < 2; kh++)
                    acc[2 + mi][nt] = __builtin_amdgcn_mfma_f32_16x16x32_bf16(
                        af[mi][kh], bfr[nt][kh], acc[2 + mi][nt], 0, 0, 0);
        __builtin_amdgcn_s_setprio(0);
        __builtin_amdgcn_s_barrier();
    }

    // ---- epilogue: Y bf16 via swizzled LDS, 16B coalesced stores ----
    {
        unsigned short* eb = lds;
#pragma unroll
        for (int mt = 0; mt < 4; mt++)
#pragma unroll
            for (int nt = 0; nt < 4; nt++) {
                int col = wn + nt * 16 + l16;
                float bv = bias[n0 + col];
                int cc = col >> 3, cw = col & 7;
#pragma unroll
                for (int r = 0; r < 4; r++) {
                    int row = wm + mt * 16 + quad * 4 + r;
                    eb[row * 256 + (((cc ^ (row & 7)) << 3) + cw)] = f2b(acc[mt][nt][r] + bv);
                }
            }
        __syncthreads();
#pragma unroll
        for (int it = 0; it < 8; it++) {
            int cid = it * 512 + tid;
            int row = cid >> 5, j = cid & 31;
            bf16x8 v = *(const bf16x8*)&eb[row * 256 + ((j ^ (row & 7)) << 3)];
            *(bf16x8*)&Y[(size_t)(m0 + row) * N1 + n0 + j * 8] = v;
        }
    }

    // ---- fused a-sum accumulators (proven mapping; wm in {0,64}) ----
    if (DO_SUMS) {
        int b = m0 >> 10;
        int wlo = (m0 & 1023) >> 5;
#pragma unroll
        for (int nt = 0; nt < 4; nt++) {
            int n = n0 + wn + nt * 16 + l16;
            float bv = bias[n];
            float tT = 0.f;
#pragma unroll
            for (int mt = 0; mt < 4; mt++)
#pragma unroll
                for (int r = 0; r < 4; r++) tT += acc[mt][nt][r] + bv;
            tT += __shfl_xor(tT, 16);
            tT += __shfl_xor(tT, 32);
            if (quad == 0) {
                atomicAdd(&Tsum[b * 1536 + n], tT);
                float th0 = acc[0][nt][0] + acc[2][nt][0] + 2.f * bv;
                atomicAdd(&H0[b * 1536 + n], th0);
            }
            if (quad == 3) {
                float th31 = acc[1][nt][3] + acc[3][nt][3] + 2.f * bv;
                atomicAdd(&H31[b * 1536 + n], th31);
            }
            if (wlo == 0 && wm == 0) {
                float tc = 0.f;
#pragma unroll
                for (int mt = 0; mt < 2; mt++)
#pragma unroll
                    for (int r = 0; r < 4; r++) tc += acc[mt][nt][r] + bv;
                tc += __shfl_xor(tc, 16);
                tc += __shfl_xor(tc, 32);
                if (quad == 0) atomicAdd(&C0[b * 1536 + n], tc);
            }
            if (wlo == 28 && wm == 64) {
                float tc = 0.f;
#pragma unroll
                for (int mt = 2; mt < 4; mt++)
#pragma unroll
                    for (int r = 0; r < 4; r++) tc += acc[mt][nt][r] + bv;
                tc += __shfl_xor(tc, 16);
                tc += __shfl_xor(tc, 32);
                if (quad == 0) atomicAdd(&C31[b * 1536 + n], tc);
            }
        }
    }
}

// ---------- gemm2 with FUSED combine+softmax in A-staging (R4-proven) + XCD swizzle ----------
__global__ __launch_bounds__(512, 2) void gemm2_fused(
    const unsigned short* __restrict__ Yg,
    const float* __restrict__ hat,
    const unsigned short* __restrict__ Wt,
    const float* __restrict__ bias,
    float* __restrict__ O)
{
    __shared__ __align__(16) unsigned short As[2 * 8192];   // 2 x 16 KB
    __shared__ __align__(16) unsigned short Bs[2 * 16384];  // 2 x 32 KB
    __shared__ float gs[3][512];                            // 6 KB
    const int tid = threadIdx.x;
    const int lane = tid & 63, wid = tid >> 6;
    const int wm = (wid >> 2) * 64;
    const int wn = (wid & 3) * 64;
    const int quad = lane >> 4, l16 = lane & 15;
    const int orig = xcd_orig(blockIdx.y * 128 + blockIdx.x, 256);
    const int m0 = (orig & 127) * 128;
    const int n0 = (orig >> 7) * 256;
    const int b = m0 >> 10, s0 = m0 & 1023, w0 = s0 >> 5;
    const int bq = b * 1024;
    const unsigned short* Bb = Wt + (size_t)n0 * 512;
    const int chunk = tid & 7, mpair = tid >> 3;

    f32x4 acc[4][4] = {};

    {
        int c = tid;
        float h0v = hat[b * 1536 + c];
        float h1v = hat[b * 1536 + 512 + c];
        float h2v = hat[b * 1536 + 1024 + c];
        float mx = fmaxf(h0v, fmaxf(h1v, h2v));
        float e0 = __expf(h0v - mx), e1 = __expf(h1v - mx), e2 = __expf(h2v - mx);
        float inv = 1.0f / (e0 + e1 + e2);
        gs[0][c] = e0 * inv; gs[1][c] = e1 * inv; gs[2][c] = e2 * inv;
    }
    __syncthreads();

    auto stageB = [&](int T) {
        unsigned short* dst = &Bs[(T & 1) * 16384];
#pragma unroll
        for (int i = 0; i < 4; i++) {
            int ch = i * 512 + tid;
            int r = ch >> 3, kc = ch & 7;
            gl_lds16(Bb + (size_t)r * 512 + T * 64 + ((kc ^ (r & 7)) * 8), dst + ch * 8);
        }
    };

    uint4 u1[2], u2[2], u3[2];
    auto issueA = [&](int Tn) {
        int q = Tn >> 1;
        int dw1 = (q == 0) ? -1 : (q == 1) ? 1 : 0;
        int dh1 = (q == 2) ? -1 : (q == 3) ? 1 : 0;
        int dh2 = (q == 0) ? -1 : (q == 1) ? 1 : 0;
        int dw2 = (q == 2) ? -1 : (q == 3) ? 1 : 0;
        int cg = Tn * 64 + chunk * 8;
#pragma unroll
        for (int j = 0; j < 2; j++) {
            int ml = mpair * 2 + j;
            int w = w0 + (ml >> 5), h = ml & 31;
            int r1 = bq + min(max(w + dw1, 0), 31) * 32 + min(max(h + dh1, 0), 31);
            int r2 = bq + min(max(w + dw2, 0), 31) * 32 + min(max(h + dh2, 0), 31);
            int r3 = bq + w * 32 + h;
            u1[j] = *(const uint4*)&Yg[(size_t)r1 * 1536 + cg];
            u2[j] = *(const uint4*)&Yg[(size_t)r2 * 1536 + 512 + cg];
            u3[j] = *(const uint4*)&Yg[(size_t)r3 * 1536 + 1024 + cg];
        }
    };
    auto writeA = [&](int Tn) {
        int cg = Tn * 64 + chunk * 8;
        float g0v[8], g1v[8], g2v[8];
        *(float4*)&g0v[0] = *(const float4*)&gs[0][cg];
        *(float4*)&g0v[4] = *(const float4*)&gs[0][cg + 4];
        *(float4*)&g1v[0] = *(const float4*)&gs[1][cg];
        *(float4*)&g1v[4] = *(const float4*)&gs[1][cg + 4];
        *(float4*)&g2v[0] = *(const float4*)&gs[2][cg];
        *(float4*)&g2v[4] = *(const float4*)&gs[2][cg + 4];
#pragma unroll
        for (int j = 0; j < 2; j++) {
            const unsigned int* a1 = (const unsigned int*)&u1[j];
            const unsigned int* a2 = (const unsigned int*)&u2[j];
            const unsigned int* a3 = (const unsigned int*)&u3[j];
            unsigned int p[4];
#pragma unroll
            for (int k = 0; k < 4; k++) {
                float lo = g0v[2 * k] * b2f(a1[k]) + g1v[2 * k] * b2f(a2[k]) + g2v[2 * k] * b2f(a3[k]);
                float hi = g0v[2 * k + 1] * b2f(a1[k] >> 16) + g1v[2 * k + 1] * b2f(a2[k] >> 16) + g2v[2 * k + 1] * b2f(a3[k] >> 16);
                p[k] = (unsigned int)f2b(lo) | ((unsigned int)f2b(hi) << 16);
            }
            int ml = mpair * 2 + j;
            *(uint4*)&As[(Tn & 1) * 8192 + ml * 64 + ((chunk ^ (ml & 7)) * 8)] = *(const uint4*)p;
        }
    };

    stageB(0);
    issueA(0);
    stageB(1);
    asm volatile("s_waitcnt vmcnt(4)" ::: "memory");
    writeA(0);
    asm volatile("s_waitcnt lgkmcnt(0)" ::: "memory");
    __builtin_amdgcn_s_barrier();

    for (int T = 0; T < 8; T++) {
        const unsigned short* Asl = &As[(T & 1) * 8192];
        const unsigned short* Bsl = &Bs[(T & 1) * 16384];
        bf16x8 bfr[4][2], af[2][2];
#pragma unroll
        for (int nt = 0; nt < 4; nt++)
#pragma unroll
            for (int kh = 0; kh < 2; kh++) {
                int rb = wn + nt * 16 + l16;
                bfr[nt][kh] = *(const bf16x8*)&Bsl[rb * 64 + (((kh * 4 + quad) ^ (rb & 7)) * 8)];
            }
#pragma unroll
        for (int mi = 0; mi < 2; mi++)
#pragma unroll
            for (int kh = 0; kh < 2; kh++) {
                int ra = wm + mi * 16 + l16;
                af[mi][kh] = *(const bf16x8*)&Asl[ra * 64 + (((kh * 4 + quad) ^ (ra & 7)) * 8)];
            }
        if (T < 7) issueA(T + 1);
        __builtin_amdgcn_s_barrier();
        asm volatile("s_waitcnt lgkmcnt(0)" ::: "memory");
        __builtin_amdgcn_sched_barrier(0);
        __builtin_amdgcn_s_setprio(1);
#pragma unroll
        for (int mi = 0; mi < 2; mi++)
#pragma unroll
            for (int nt = 0; nt < 4; nt++)
#pragma unroll
                for (int kh = 0; kh < 2; kh++)
                    acc[mi][nt] = __builtin_amdgcn_mfma_f32_16x16x32_bf16(
                        af[mi][kh], bfr[nt][kh], acc[mi][nt], 0, 0, 0);
        __builtin_amdgcn_s_setprio(0);
        __builtin_amdgcn_s_barrier();
#pragma unroll
        for (int mi = 0; mi < 2; mi++)
#pragma unroll
            for (int kh = 0; kh < 2; kh++) {
                int ra = wm + (2 + mi) * 16 + l16;
                af[mi][kh] = *(const bf16x8*)&Asl[ra * 64 + (((kh * 4 + quad) ^ (ra & 7)) * 8)];
            }
        if (T < 6) stageB(T + 2);
        if (T < 7) {
            if (T < 6) asm volatile("s_waitcnt vmcnt(4)" ::: "memory");
            else       asm volatile("s_waitcnt vmcnt(0)" ::: "memory");
            writeA(T + 1);
        }
        __builtin_amdgcn_s_barrier();
        asm volatile("s_waitcnt lgkmcnt(0)" ::: "memory");
        __builtin_amdgcn_sched_barrier(0);
        __builtin_amdgcn_s_setprio(1);
#pragma unroll
        for (int mi = 0; mi < 2; mi++)
#pragma unroll
            for (int nt = 0; nt < 4; nt++)
#pragma unroll
                for (int kh = 0; kh < 2; kh++)
                    acc[2 + mi][nt] = __builtin_amdgcn_mfma_f32_16x16x32_bf16(
                        af[mi][kh], bfr[nt][kh], acc[2 + mi][nt], 0, 0, 0);
        __builtin_amdgcn_s_setprio(0);
        __builtin_amdgcn_s_barrier();
    }

    float* ef = (float*)Bs;
#pragma unroll
    for (int p = 0; p < 2; p++) {
        if (((wid & 3) >> 1) == p) {
#pragma unroll
            for (int mt = 0; mt < 4; mt++)
#pragma unroll
                for (int nt = 0; nt < 4; nt++) {
                    int nl = wn - p * 128 + nt * 16 + l16;
                    float bv = bias[n0 + p * 128 + nl];
                    int c = (wm >> 2) + mt * 4 + quad;
                    f32x4 v;
#pragma unroll
                    for (int r = 0; r < 4; r++) v[r] = acc[mt][nt][r] + bv;
                    *(f32x4*)&ef[nl * 128 + ((c ^ (nl & 7)) << 2)] = v;
                }
        }
        __syncthreads();
#pragma unroll
        for (int it = 0; it < 8; it++) {
            int cid = it * 512 + tid;
            int nl = cid >> 5, j = cid & 31;
            f32x4 v = *(const f32x4*)&ef[nl * 128 + ((j ^ (nl & 7)) << 2)];
            *(f32x4*)&O[((size_t)(b * 512 + n0 + p * 128 + nl)) * 1024 + s0 + j * 4] = v;
        }
        if (p == 0) __syncthreads();
    }
}

// ---------- layer1 ----------
__global__ __launch_bounds__(256) void mlp_layer1(
    const float* __restrict__ sums, const float* __restrict__ wa,
    const float* __restrict__ ba, float* __restrict__ h)
{
    __shared__ float sa[512];
    int b = blockIdx.x >> 7;
    int t = threadIdx.x;
    const float* Tp   = sums;
    const float* H0p  = sums + 24576;
    const float* H31p = sums + 49152;
    const float* C0p  = sums + 73728;
    const float* C31p = sums + 98304;
#pragma unroll
    for (int j = 0; j < 2; j++) {
        int c = t + j * 256;
        int q = c >> 7;
        int n1 = b * 1536 + c;
        float t123 = Tp[n1] + Tp[n1 + 512] + Tp[n1 + 1024];
        float sC1 = C0p[n1] - C31p[n1];
        float sH1 = H0p[n1] - H31p[n1];
        float sC2 = C0p[n1 + 512] - C31p[n1 + 512];
        float sH2 = H0p[n1 + 512] - H31p[n1 + 512];
        float e = (q < 2) ? (sC1 + sH2) : (sH1 + sC2);
        sa[c] = t123 + ((q & 1) ? -e : e);
    }
    __syncthreads();
    int lane = t & 63, wid = t >> 6;
    int o = (blockIdx.x & 127) * 4 + wid;
    const float4* wr = (const float4*)(wa + (size_t)o * 512);
    float4 w0 = wr[lane * 2], w1v = wr[lane * 2 + 1];
    float4 a0 = ((const float4*)sa)[lane * 2], a1 = ((const float4*)sa)[lane * 2 + 1];
    float dot = w0.x * a0.x + w0.y * a0.y + w0.z * a0.z + w0.w * a0.w
              + w1v.x * a1.x + w1v.y * a1.y + w1v.z * a1.z + w1v.w * a1.w;
#pragma unroll
    for (int off = 32; off; off >>= 1) dot += __shfl_down(dot, off);
    if (lane == 0) {
        float v = dot + ba[o];
        h[b * 512 + o] = 0.5f * v * (1.0f + erff(v * 0.7071067811865475f));
    }
}

// ---------- layer2: h staged in LDS; 16 o's per block (4 per wave) ----------
__global__ __launch_bounds__(256) void mlp_layer2(
    const float* __restrict__ h, const float* __restrict__ wb,
    const float* __restrict__ bb, float* __restrict__ hat)
{
    __shared__ float sh[512];
    int b = blockIdx.x / 96;
    int og = blockIdx.x - b * 96;
    int t = threadIdx.x;
    sh[t] = h[b * 512 + t];
    sh[t + 256] = h[b * 512 + 256 + t];
    __syncthreads();
    int lane = t & 63, wid = t >> 6;
    float4 a0 = ((const float4*)sh)[lane * 2], a1 = ((const float4*)sh)[lane * 2 + 1];
#pragma unroll
    for (int i = 0; i < 4; i++) {
        int o = og * 16 + wid * 4 + i;
        const float4* wr = (const float4*)(wb + (size_t)o * 512);
        float4 w0 = wr[lane * 2], w1 = wr[lane * 2 + 1];
        float dot = w0.x * a0.x + w0.y * a0.y + w0.z * a0.z + w0.w * a0.w
                  + w1.x * a1.x + w1.y * a1.y + w1.z * a1.z + w1.w * a1.w;
#pragma unroll
        for (int off = 32; off; off >>= 1) dot += __shfl_down(dot, off);
        if (lane == 0)
            hat[(size_t)b * 1536 + o] = dot + bb[o];
    }
}

extern "C" void kernel_launch(void* const* d_in, const int* in_sizes, int n_in,
                              void* d_out, int out_size, void* d_ws, size_t ws_size,
                              hipStream_t stream) {
    const float* x  = (const float*)d_in[0];
    const float* w1 = (const float*)d_in[1];
    const float* b1 = (const float*)d_in[2];
    const float* wa = (const float*)d_in[3];
    const float* ba = (const float*)d_in[4];
    const float* wb = (const float*)d_in[5];
    const float* bb = (const float*)d_in[6];
    const float* w2 = (const float*)d_in[7];
    const float* b2 = (const float*)d_in[8];
    float* out = (float*)d_out;

    char* ws = (char*)d_ws;
    unsigned short* xT   = (unsigned short*)(ws);              // 16 MB (dead after gemm1)
    unsigned short* w1b  = (unsigned short*)(ws + 16777216);   // 1.5 MB
    unsigned short* w2b  = (unsigned short*)(ws + 18350080);   // 0.5 MB
    unsigned short* y    = (unsigned short*)(ws + 18874368);   // 48 MB: (B,S,3C) bf16
    float* sums          = (float*)(ws + 69206016);            // 5 x 96 KB
    float* h_buf         = (float*)(ws + 69697536);            // 32 KB
    float* hat_buf       = (float*)(ws + 69730304);            // 96 KB

    float* Tsum = sums;
    float* H0   = sums + 24576;
    float* H31  = sums + 49152;
    float* C0   = sums + 73728;
    float* C31  = sums + 98304;

    transpose_convert_x<<<dim3(16, 8, 17), dim3(256), 0, stream>>>(
        x, xT, w1, w2, w1b, w2b, sums);
    gemm_2ph<true><<<dim3(128, 6), dim3(512), 0, stream>>>(
        xT, w1b, b1, y, Tsum, H0, H31, C0, C31);
    mlp_layer1<<<dim3(2048), dim3(256), 0, stream>>>(sums, wa, ba, h_buf);
    mlp_layer2<<<dim3(1536), dim3(256), 0, stream>>>(h_buf, wb, bb, hat_buf);
    gemm2_fused<<<dim3(128, 2), dim3(512), 0, stream>>>(
        y, hat_buf, w2b, b2, out);
}

// Round 10
// 178.095 us; speedup vs baseline: 1.0674x; 1.0305x over previous
//
#include <hip/hip_runtime.h>
#include <stdint.h>

typedef __bf16 bf16x8 __attribute__((ext_vector_type(8)));
typedef float f32x4 __attribute__((ext_vector_type(4)));

#define B_ 16
#define C_ 512
#define S_ 1024   // W*H = 32*32
#define N1 1536   // 3C

// ---------- bf16 helpers (manual RNE) ----------
__device__ inline unsigned short f2b(float f) {
    unsigned int u = __builtin_bit_cast(unsigned int, f);
    unsigned int lsb = (u >> 16) & 1u;
    u += 0x7fffu + lsb;
    return (unsigned short)(u >> 16);
}
__device__ inline float b2f(unsigned int s) {
    unsigned int u = (s & 0xffffu) << 16;
    return __builtin_bit_cast(float, u);
}

// async global->LDS, 16B per lane. LDS dest must be wave-uniform base + lane*16.
__device__ inline void gl_lds16(const unsigned short* g, unsigned short* l) {
    __builtin_amdgcn_global_load_lds(
        (const __attribute__((address_space(1))) void*)(g),
        (__attribute__((address_space(3))) void*)(l),
        16, 0, 0);
}

// ---------- prep: x (B,C,S) f32 -> xT (B,S,C) bf16 (vectorized), + fused misc ----------
// grid (16, 8, 17), block 256. z<16: transpose 64s x 64c tile. z==16: misc (grid-stride).
__global__ __launch_bounds__(256) void transpose_convert_x(
    const float* __restrict__ x, unsigned short* __restrict__ xT,
    const float* __restrict__ w1, const float* __restrict__ w2,
    unsigned short* __restrict__ w1b, unsigned short* __restrict__ w2b,
    float* __restrict__ sums)
{
    int t = threadIdx.x;
    if (blockIdx.z == 16) {
        int base = (blockIdx.y * 16 + blockIdx.x) * 256 + t; // 32768 threads
        for (int i = base; i < 292864; i += 32768) {
            if (i < 196608) {
                float4 v = ((const float4*)w1)[i];
                ((ushort4*)w1b)[i] = make_ushort4(f2b(v.x), f2b(v.y), f2b(v.z), f2b(v.w));
            } else if (i < 262144) {
                int j = i - 196608;
                float4 v = ((const float4*)w2)[j];
                ((ushort4*)w2b)[j] = make_ushort4(f2b(v.x), f2b(v.y), f2b(v.z), f2b(v.w));
            } else {
                int j = i - 262144;
                ((float4*)sums)[j] = make_float4(0.f, 0.f, 0.f, 0.f);
            }
        }
        return;
    }
    __shared__ float tile[64][68];
    int b = blockIdx.z;
    int c0 = blockIdx.y * 64;
    int s0 = blockIdx.x * 64;
    int r = t >> 2, q4 = t & 3;
    const float* xp = x + ((size_t)(b * C_ + c0 + r)) * S_ + s0;
#pragma unroll
    for (int k = 0; k < 4; k++) {
        float4 v = ((const float4*)xp)[q4 + 4 * k];
        *(float4*)&tile[r][(q4 + 4 * k) * 4] = v;
    }
    __syncthreads();
    int sr = t >> 2; // output s-row
    unsigned short* op = xT + ((size_t)(b * S_ + s0 + sr)) * C_ + c0;
#pragma unroll
    for (int kk = 0; kk < 2; kk++) {
        int chunk = q4 + 4 * kk;
        unsigned int pz[4];
#pragma unroll
        for (int i2 = 0; i2 < 4; i2++) {
            int c = chunk * 8 + i2 * 2;
            pz[i2] = (unsigned int)f2b(tile[c][sr]) | ((unsigned int)f2b(tile[c + 1][sr]) << 16);
        }
        *(uint4*)&op[chunk * 8] = make_uint4(pz[0], pz[1], pz[2], pz[3]);
    }
}

// ---------- gemm1: 128x256 tile, BK=64, 8 waves, 2-phase counted-vmcnt (R3, proven) ----------
template <bool TRANS_OUT, bool DO_SUMS>
__global__ __launch_bounds__(512, 2) void gemm_2ph(
    const unsigned short* __restrict__ A,
    const unsigned short* __restrict__ Wt,
    const float* __restrict__ bias,
    void* __restrict__ Cout,
    float* __restrict__ Tsum, float* __restrict__ H0, float* __restrict__ H31,
    float* __restrict__ C0, float* __restrict__ C31)
{
    __shared__ __align__(16) unsigned short lds[49152]; // 96 KB
    const int tid = threadIdx.x;
    const int lane = tid & 63, wid = tid >> 6;
    const int wm = (wid >> 2) * 64;   // 0 / 64
    const int wn = (wid & 3) * 64;    // 0,64,128,192
    const int quad = lane >> 4, l16 = lane & 15;
    const int m0 = blockIdx.x * 128;
    const int n0 = blockIdx.y * 256;
    const unsigned short* Ab = A + (size_t)m0 * 512;
    const unsigned short* Bb = Wt + (size_t)n0 * 512;

    f32x4 acc[4][4] = {};

    auto stageA = [&](int T) {
        unsigned short* dst = &lds[(T & 1) * 8192];
#pragma unroll
        for (int i = 0; i < 2; i++) {
            int ch = i * 512 + tid;
            int r = ch >> 3, kc = ch & 7;
            gl_lds16(Ab + (size_t)r * 512 + T * 64 + ((kc ^ (r & 7)) * 8), dst + ch * 8);
        }
    };
    auto stageB = [&](int T) {
        unsigned short* dst = &lds[16384 + (T & 1) * 16384];
#pragma unroll
        for (int i = 0; i < 4; i++) {
            int ch = i * 512 + tid;
            int r = ch >> 3, kc = ch & 7;
            gl_lds16(Bb + (size_t)r * 512 + T * 64 + ((kc ^ (r & 7)) * 8), dst + ch * 8);
        }
    };

    stageB(0); stageA(0); stageB(1);
    asm volatile("s_waitcnt vmcnt(4)" ::: "memory");
    __builtin_amdgcn_s_barrier();

    for (int T = 0; T < 8; T++) {
        const unsigned short* Asl = &lds[(T & 1) * 8192];
        const unsigned short* Bsl = &lds[16384 + (T & 1) * 16384];
        bf16x8 bfr[4][2], af[2][2];
        // ---- phase 0 ----
#pragma unroll
        for (int nt = 0; nt < 4; nt++)
#pragma unroll
            for (int kh = 0; kh < 2; kh++) {
                int rb = wn + nt * 16 + l16;
                bfr[nt][kh] = *(const bf16x8*)&Bsl[rb * 64 + (((kh * 4 + quad) ^ (rb & 7)) * 8)];
            }
#pragma unroll
        for (int mi = 0; mi < 2; mi++)
#pragma unroll
            for (int kh = 0; kh < 2; kh++) {
                int ra = wm + mi * 16 + l16;
                af[mi][kh] = *(const bf16x8*)&Asl[ra * 64 + (((kh * 4 + quad) ^ (ra & 7)) * 8)];
            }
        if (T < 7) stageA(T + 1);
        __builtin_amdgcn_s_barrier();
        asm volatile("s_waitcnt lgkmcnt(0)" ::: "memory");
        __builtin_amdgcn_sched_barrier(0);
        __builtin_amdgcn_s_setprio(1);
#pragma unroll
        for (int mi = 0; mi < 2; mi++)
#pragma unroll
            for (int nt = 0; nt < 4; nt++)
#pragma unroll
                for (int kh = 0; kh < 2; kh++)
                    acc[mi][nt] = __builtin_amdgcn_mfma_f32_16x16x32_bf16(
                        af[mi][kh], bfr[nt][kh], acc[mi][nt], 0, 0, 0);
        __builtin_amdgcn_s_setprio(0);
        __builtin_amdgcn_s_barrier();
        // ---- phase 1 ----
#pragma unroll
        for (int mi = 0; mi < 2; mi++)
#pragma unroll
            for (int kh = 0; kh < 2; kh++) {
                int ra = wm + (2 + mi) * 16 + l16;
                af[mi][kh] = *(const bf16x8*)&Asl[ra * 64 + (((kh * 4 + quad) ^ (ra & 7)) * 8)];
            }
        if (T < 6) {
            stageB(T + 2);
            asm volatile("s_waitcnt vmcnt(4)" ::: "memory");
        } else if (T == 6) {
            asm volatile("s_waitcnt vmcnt(0)" ::: "memory");
        }
        __builtin_amdgcn_s_barrier();
        asm volatile("s_waitcnt lgkmcnt(0)" ::: "memory");
        __builtin_amdgcn_sched_barrier(0);
        __builtin_amdgcn_s_setprio(1);
#pragma unroll
        for (int mi = 0; mi < 2; mi++)
#pragma unroll
            for (int nt = 0; nt < 4; nt++)
#pragma unroll
                for (int kh = 0; kh < 2; kh++)
                    acc[2 + mi][nt] = __builtin_amdgcn_mfma_f32_16x16x32_bf16(
                        af[mi][kh], bfr[nt][kh], acc[2 + mi][nt], 0, 0, 0);
        __builtin_amdgcn_s_setprio(0);
        __builtin_amdgcn_s_barrier();
    }

    // ---- epilogue ----
    if (!TRANS_OUT) {
        unsigned short* eb = lds;
#pragma unroll
        for (int mt = 0; mt < 4; mt++)
#pragma unroll
            for (int nt = 0; nt < 4; nt++) {
                int col = wn + nt * 16 + l16;
                float bv = bias[n0 + col];
                int cc = col >> 3, cw = col & 7;
#pragma unroll
                for (int r = 0; r < 4; r++) {
                    int row = wm + mt * 16 + quad * 4 + r;
                    eb[row * 256 + (((cc ^ (row & 7)) << 3) + cw)] = f2b(acc[mt][nt][r] + bv);
                }
            }
        __syncthreads();
        unsigned short* Y = (unsigned short*)Cout;
#pragma unroll
        for (int it = 0; it < 8; it++) {
            int cid = it * 512 + tid;
            int row = cid >> 5, j = cid & 31;
            bf16x8 v = *(const bf16x8*)&eb[row * 256 + ((j ^ (row & 7)) << 3)];
            *(bf16x8*)&Y[(size_t)(m0 + row) * N1 + n0 + j * 8] = v;
        }
    } else {
        float* ef = (float*)lds;
        int b = m0 >> 10, s0r = m0 & 1023;
        float* O = (float*)Cout;
#pragma unroll
        for (int p = 0; p < 2; p++) {
            if (((wid & 3) >> 1) == p) {
#pragma unroll
                for (int mt = 0; mt < 4; mt++)
#pragma unroll
                    for (int nt = 0; nt < 4; nt++) {
                        int nl = wn - p * 128 + nt * 16 + l16;
                        float bv = bias[n0 + p * 128 + nl];
                        int c = (wm >> 2) + mt * 4 + quad;
                        f32x4 v;
#pragma unroll
                        for (int r = 0; r < 4; r++) v[r] = acc[mt][nt][r] + bv;
                        *(f32x4*)&ef[nl * 128 + ((c ^ (nl & 7)) << 2)] = v;
                    }
            }
            __syncthreads();
#pragma unroll
            for (int it = 0; it < 8; it++) {
                int cid = it * 512 + tid;
                int nl = cid >> 5, j = cid & 31;
                f32x4 v = *(const f32x4*)&ef[nl * 128 + ((j ^ (nl & 7)) << 2)];
                *(f32x4*)&O[((size_t)(b * 512 + n0 + p * 128 + nl)) * 1024 + s0r + j * 4] = v;
            }
            if (p == 0) __syncthreads();
        }
    }

    if (DO_SUMS) {
        int b = m0 >> 10;
        int wlo = (m0 & 1023) >> 5;
#pragma unroll
        for (int nt = 0; nt < 4; nt++) {
            int n = n0 + wn + nt * 16 + l16;
            float bv = bias[n];
            float tT = 0.f;
#pragma unroll
            for (int mt = 0; mt < 4; mt++)
#pragma unroll
                for (int r = 0; r < 4; r++) tT += acc[mt][nt][r] + bv;
            tT += __shfl_xor(tT, 16);
            tT += __shfl_xor(tT, 32);
            if (quad == 0) {
                atomicAdd(&Tsum[b * 1536 + n], tT);
                float th0 = acc[0][nt][0] + acc[2][nt][0] + 2.f * bv;
                atomicAdd(&H0[b * 1536 + n], th0);
            }
            if (quad == 3) {
                float th31 = acc[1][nt][3] + acc[3][nt][3] + 2.f * bv;
                atomicAdd(&H31[b * 1536 + n], th31);
            }
            if (wlo == 0 && wm == 0) {
                float tc = 0.f;
#pragma unroll
                for (int mt = 0; mt < 2; mt++)
#pragma unroll
                    for (int r = 0; r < 4; r++) tc += acc[mt][nt][r] + bv;
                tc += __shfl_xor(tc, 16);
                tc += __shfl_xor(tc, 32);
                if (quad == 0) atomicAdd(&C0[b * 1536 + n], tc);
            }
            if (wlo == 28 && wm == 64) {
                float tc = 0.f;
#pragma unroll
                for (int mt = 2; mt < 4; mt++)
#pragma unroll
                    for (int r = 0; r < 4; r++) tc += acc[mt][nt][r] + bv;
                tc += __shfl_xor(tc, 16);
                tc += __shfl_xor(tc, 32);
                if (quad == 0) atomicAdd(&C31[b * 1536 + n], tc);
            }
        }
    }
}

// ---------- gemm2 with FUSED combine+softmax in A-staging ----------
// A[m][c] = g0[b,c]*y[shift1(s),c] + g1[b,c]*y[shift2(s),512+c] + g2[b,c]*y[s,1024+c]
// staged reg->LDS (T14): issue 6 y-loads in ph0, combine + 2 ds_write_b128 in ph1.
// B = w2b via gl_lds16 (as gemm1). Output: TRANS f32 via LDS.
__global__ __launch_bounds__(512, 2) void gemm2_fused(
    const unsigned short* __restrict__ Yg,
    const float* __restrict__ hat,
    const unsigned short* __restrict__ Wt,
    const float* __restrict__ bias,
    float* __restrict__ O)
{
    __shared__ __align__(16) unsigned short As[2 * 8192];   // 2 x 16 KB
    __shared__ __align__(16) unsigned short Bs[2 * 16384];  // 2 x 32 KB
    __shared__ float gs[3][512];                            // 6 KB
    const int tid = threadIdx.x;
    const int lane = tid & 63, wid = tid >> 6;
    const int wm = (wid >> 2) * 64;
    const int wn = (wid & 3) * 64;
    const int quad = lane >> 4, l16 = lane & 15;
    const int m0 = blockIdx.x * 128;
    const int n0 = blockIdx.y * 256;
    const int b = m0 >> 10, s0 = m0 & 1023, w0 = s0 >> 5;
    const int bq = b * 1024;
    const unsigned short* Bb = Wt + (size_t)n0 * 512;
    const int chunk = tid & 7, mpair = tid >> 3;

    f32x4 acc[4][4] = {};

    {
        int c = tid;
        float h0v = hat[b * 1536 + c];
        float h1v = hat[b * 1536 + 512 + c];
        float h2v = hat[b * 1536 + 1024 + c];
        float mx = fmaxf(h0v, fmaxf(h1v, h2v));
        float e0 = __expf(h0v - mx), e1 = __expf(h1v - mx), e2 = __expf(h2v - mx);
        float inv = 1.0f / (e0 + e1 + e2);
        gs[0][c] = e0 * inv; gs[1][c] = e1 * inv; gs[2][c] = e2 * inv;
    }
    __syncthreads();

    auto stageB = [&](int T) {
        unsigned short* dst = &Bs[(T & 1) * 16384];
#pragma unroll
        for (int i = 0; i < 4; i++) {
            int ch = i * 512 + tid;
            int r = ch >> 3, kc = ch & 7;
            gl_lds16(Bb + (size_t)r * 512 + T * 64 + ((kc ^ (r & 7)) * 8), dst + ch * 8);
        }
    };

    uint4 u1[2], u2[2], u3[2];
    auto issueA = [&](int Tn) {
        int q = Tn >> 1;
        int dw1 = (q == 0) ? -1 : (q == 1) ? 1 : 0;
        int dh1 = (q == 2) ? -1 : (q == 3) ? 1 : 0;
        int dh2 = (q == 0) ? -1 : (q == 1) ? 1 : 0;
        int dw2 = (q == 2) ? -1 : (q == 3) ? 1 : 0;
        int cg = Tn * 64 + chunk * 8;
#pragma unroll
        for (int j = 0; j < 2; j++) {
            int ml = mpair * 2 + j;
            int w = w0 + (ml >> 5), h = ml & 31;
            int r1 = bq + min(max(w + dw1, 0), 31) * 32 + min(max(h + dh1, 0), 31);
            int r2 = bq + min(max(w + dw2, 0), 31) * 32 + min(max(h + dh2, 0), 31);
            int r3 = bq + w * 32 + h;
            u1[j] = *(const uint4*)&Yg[(size_t)r1 * 1536 + cg];
            u2[j] = *(const uint4*)&Yg[(size_t)r2 * 1536 + 512 + cg];
            u3[j] = *(const uint4*)&Yg[(size_t)r3 * 1536 + 1024 + cg];
        }
    };
    auto writeA = [&](int Tn) {
        int cg = Tn * 64 + chunk * 8;
        float g0v[8], g1v[8], g2v[8];
        *(float4*)&g0v[0] = *(const float4*)&gs[0][cg];
        *(float4*)&g0v[4] = *(const float4*)&gs[0][cg + 4];
        *(float4*)&g1v[0] = *(const float4*)&gs[1][cg];
        *(float4*)&g1v[4] = *(const float4*)&gs[1][cg + 4];
        *(float4*)&g2v[0] = *(const float4*)&gs[2][cg];
        *(float4*)&g2v[4] = *(const float4*)&gs[2][cg + 4];
#pragma unroll
        for (int j = 0; j < 2; j++) {
            const unsigned int* a1 = (const unsigned int*)&u1[j];
            const unsigned int* a2 = (const unsigned int*)&u2[j];
            const unsigned int* a3 = (const unsigned int*)&u3[j];
            unsigned int p[4];
#pragma unroll
            for (int k = 0; k < 4; k++) {
                float lo = g0v[2 * k] * b2f(a1[k]) + g1v[2 * k] * b2f(a2[k]) + g2v[2 * k] * b2f(a3[k]);
                float hi = g0v[2 * k + 1] * b2f(a1[k] >> 16) + g1v[2 * k + 1] * b2f(a2[k] >> 16) + g2v[2 * k + 1] * b2f(a3[k] >> 16);
                p[k] = (unsigned int)f2b(lo) | ((unsigned int)f2b(hi) << 16);
            }
            int ml = mpair * 2 + j;
            *(uint4*)&As[(Tn & 1) * 8192 + ml * 64 + ((chunk ^ (ml & 7)) * 8)] = *(const uint4*)p;
        }
    };

    // prologue: B0, y0-loads, B1; wait B0+y0 (keep B1 in flight); build As[0]
    stageB(0);
    issueA(0);
    stageB(1);
    asm volatile("s_waitcnt vmcnt(4)" ::: "memory");
    writeA(0);
    asm volatile("s_waitcnt lgkmcnt(0)" ::: "memory");
    __builtin_amdgcn_s_barrier();

    for (int T = 0; T < 8; T++) {
        const unsigned short* Asl = &As[(T & 1) * 8192];
        const unsigned short* Bsl = &Bs[(T & 1) * 16384];
        bf16x8 bfr[4][2], af[2][2];
        // ---- phase 0 ----
#pragma unroll
        for (int nt = 0; nt < 4; nt++)
#pragma unroll
            for (int kh = 0; kh < 2; kh++) {
                int rb = wn + nt * 16 + l16;
                bfr[nt][kh] = *(const bf16x8*)&Bsl[rb * 64 + (((kh * 4 + quad) ^ (rb & 7)) * 8)];
            }
#pragma unroll
        for (int mi = 0; mi < 2; mi++)
#pragma unroll
            for (int kh = 0; kh < 2; kh++) {
                int ra = wm + mi * 16 + l16;
                af[mi][kh] = *(const bf16x8*)&Asl[ra * 64 + (((kh * 4 + quad) ^ (ra & 7)) * 8)];
            }
        if (T < 7) issueA(T + 1);
        __builtin_amdgcn_s_barrier();
        asm volatile("s_waitcnt lgkmcnt(0)" ::: "memory");
        __builtin_amdgcn_sched_barrier(0);
        __builtin_amdgcn_s_setprio(1);
#pragma unroll
        for (int mi = 0; mi < 2; mi++)
#pragma unroll
            for (int nt = 0; nt < 4; nt++)
#pragma unroll
                for (int kh = 0; kh < 2; kh++)
                    acc[mi][nt] = __builtin_amdgcn_mfma_f32_16x16x32_bf16(
                        af[mi][kh], bfr[nt][kh], acc[mi][nt], 0, 0, 0);
        __builtin_amdgcn_s_setprio(0);
        __builtin_amdgcn_s_barrier();
        // ---- phase 1 ----
#pragma unroll
        for (int mi = 0; mi < 2; mi++)
#pragma unroll
            for (int kh = 0; kh < 2; kh++) {
                int ra = wm + (2 + mi) * 16 + l16;
                af[mi][kh] = *(const bf16x8*)&Asl[ra * 64 + (((kh * 4 + quad) ^ (ra & 7)) * 8)];
            }
        if (T < 6) stageB(T + 2);
        if (T < 7) {
            if (T < 6) asm volatile("s_waitcnt vmcnt(4)" ::: "memory");
            else       asm volatile("s_waitcnt vmcnt(0)" ::: "memory");
            writeA(T + 1);
        }
        __builtin_amdgcn_s_barrier();
        asm volatile("s_waitcnt lgkmcnt(0)" ::: "memory");
        __builtin_amdgcn_sched_barrier(0);
        __builtin_amdgcn_s_setprio(1);
#pragma unroll
        for (int mi = 0; mi < 2; mi++)
#pragma unroll
            for (int nt = 0; nt < 4; nt++)
#pragma unroll
                for (int kh = 0; kh < 2; kh++)
                    acc[2 + mi][nt] = __builtin_amdgcn_mfma_f32_16x16x32_bf16(
                        af[mi][kh], bfr[nt][kh], acc[2 + mi][nt], 0, 0, 0);
        __builtin_amdgcn_s_setprio(0);
        __builtin_amdgcn_s_barrier();
    }

    // ---- epilogue: transpose (n,s) via LDS, 2 passes of 128 n-rows ----
    float* ef = (float*)Bs; // 64 KB
#pragma unroll
    for (int p = 0; p < 2; p++) {
        if (((wid & 3) >> 1) == p) {
#pragma unroll
            for (int mt = 0; mt < 4; mt++)
#pragma unroll
                for (int nt = 0; nt < 4; nt++) {
                    int nl = wn - p * 128 + nt * 16 + l16;
                    float bv = bias[n0 + p * 128 + nl];
                    int c = (wm >> 2) + mt * 4 + quad;
                    f32x4 v;
#pragma unroll
                    for (int r = 0; r < 4; r++) v[r] = acc[mt][nt][r] + bv;
                    *(f32x4*)&ef[nl * 128 + ((c ^ (nl & 7)) << 2)] = v;
                }
        }
        __syncthreads();
#pragma unroll
        for (int it = 0; it < 8; it++) {
            int cid = it * 512 + tid;
            int nl = cid >> 5, j = cid & 31;
            f32x4 v = *(const f32x4*)&ef[nl * 128 + ((j ^ (nl & 7)) << 2)];
            *(f32x4*)&O[((size_t)(b * 512 + n0 + p * 128 + nl)) * 1024 + s0 + j * 4] = v;
        }
        if (p == 0) __syncthreads();
    }
}

// ---------- layer1 ----------
__global__ __launch_bounds__(256) void mlp_layer1(
    const float* __restrict__ sums, const float* __restrict__ wa,
    const float* __restrict__ ba, float* __restrict__ h)
{
    __shared__ float sa[512];
    int b = blockIdx.x >> 7;
    int t = threadIdx.x;
    const float* Tp   = sums;
    const float* H0p  = sums + 24576;
    const float* H31p = sums + 49152;
    const float* C0p  = sums + 73728;
    const float* C31p = sums + 98304;
#pragma unroll
    for (int j = 0; j < 2; j++) {
        int c = t + j * 256;
        int q = c >> 7;
        int n1 = b * 1536 + c;
        float t123 = Tp[n1] + Tp[n1 + 512] + Tp[n1 + 1024];
        float sC1 = C0p[n1] - C31p[n1];
        float sH1 = H0p[n1] - H31p[n1];
        float sC2 = C0p[n1 + 512] - C31p[n1 + 512];
        float sH2 = H0p[n1 + 512] - H31p[n1 + 512];
        float e = (q < 2) ? (sC1 + sH2) : (sH1 + sC2);
        sa[c] = t123 + ((q & 1) ? -e : e);
    }
    __syncthreads();
    int lane = t & 63, wid = t >> 6;
    int o = (blockIdx.x & 127) * 4 + wid;
    const float4* wr = (const float4*)(wa + (size_t)o * 512);
    float4 w0 = wr[lane * 2], w1v = wr[lane * 2 + 1];
    float4 a0 = ((const float4*)sa)[lane * 2], a1 = ((const float4*)sa)[lane * 2 + 1];
    float dot = w0.x * a0.x + w0.y * a0.y + w0.z * a0.z + w0.w * a0.w
              + w1v.x * a1.x + w1v.y * a1.y + w1v.z * a1.z + w1v.w * a1.w;
#pragma unroll
    for (int off = 32; off; off >>= 1) dot += __shfl_down(dot, off);
    if (lane == 0) {
        float v = dot + ba[o];
        h[b * 512 + o] = 0.5f * v * (1.0f + erff(v * 0.7071067811865475f));
    }
}

// ---------- layer2: h staged in LDS; 16 o's per block (4 per wave) ----------
__global__ __launch_bounds__(256) void mlp_layer2(
    const float* __restrict__ h, const float* __restrict__ wb,
    const float* __restrict__ bb, float* __restrict__ hat)
{
    __shared__ float sh[512];
    int b = blockIdx.x / 96;
    int og = blockIdx.x - b * 96;
    int t = threadIdx.x;
    sh[t] = h[b * 512 + t];
    sh[t + 256] = h[b * 512 + 256 + t];
    __syncthreads();
    int lane = t & 63, wid = t >> 6;
    float4 a0 = ((const float4*)sh)[lane * 2], a1 = ((const float4*)sh)[lane * 2 + 1];
#pragma unroll
    for (int i = 0; i < 4; i++) {
        int o = og * 16 + wid * 4 + i;
        const float4* wr = (const float4*)(wb + (size_t)o * 512);
        float4 w0 = wr[lane * 2], w1 = wr[lane * 2 + 1];
        float dot = w0.x * a0.x + w0.y * a0.y + w0.z * a0.z + w0.w * a0.w
                  + w1.x * a1.x + w1.y * a1.y + w1.z * a1.z + w1.w * a1.w;
#pragma unroll
        for (int off = 32; off; off >>= 1) dot += __shfl_down(dot, off);
        if (lane == 0)
            hat[(size_t)b * 1536 + o] = dot + bb[o];
    }
}

extern "C" void kernel_launch(void* const* d_in, const int* in_sizes, int n_in,
                              void* d_out, int out_size, void* d_ws, size_t ws_size,
                              hipStream_t stream) {
    const float* x  = (const float*)d_in[0];
    const float* w1 = (const float*)d_in[1];
    const float* b1 = (const float*)d_in[2];
    const float* wa = (const float*)d_in[3];
    const float* ba = (const float*)d_in[4];
    const float* wb = (const float*)d_in[5];
    const float* bb = (const float*)d_in[6];
    const float* w2 = (const float*)d_in[7];
    const float* b2 = (const float*)d_in[8];
    float* out = (float*)d_out;

    char* ws = (char*)d_ws;
    unsigned short* xT   = (unsigned short*)(ws);              // 16 MB (dead after gemm1)
    unsigned short* w1b  = (unsigned short*)(ws + 16777216);   // 1.5 MB
    unsigned short* w2b  = (unsigned short*)(ws + 18350080);   // 0.5 MB
    unsigned short* y    = (unsigned short*)(ws + 18874368);   // 48 MB: (B,S,3C) bf16
    float* sums          = (float*)(ws + 69206016);            // 5 x 96 KB
    float* h_buf         = (float*)(ws + 69697536);            // 32 KB
    float* hat_buf       = (float*)(ws + 69730304);            // 96 KB

    float* Tsum = sums;
    float* H0   = sums + 24576;
    float* H31  = sums + 49152;
    float* C0   = sums + 73728;
    float* C31  = sums + 98304;

    transpose_convert_x<<<dim3(16, 8, 17), dim3(256), 0, stream>>>(
        x, xT, w1, w2, w1b, w2b, sums);
    gemm_2ph<false, true><<<dim3(128, 6), dim3(512), 0, stream>>>(
        xT, w1b, b1, (void*)y, Tsum, H0, H31, C0, C31);
    mlp_layer1<<<dim3(2048), dim3(256), 0, stream>>>(sums, wa, ba, h_buf);
    mlp_layer2<<<dim3(1536), dim3(256), 0, stream>>>(h_buf, wb, bb, hat_buf);
    gemm2_fused<<<dim3(128, 2), dim3(512), 0, stream>>>(
        y, hat_buf, w2b, b2, out);
}